// Round 1
// baseline (426.005 us; speedup 1.0000x reference)
//
#include <hip/hip_runtime.h>
#include <math.h>

// Problem constants (from reference)
#define L_LEN     120000
#define BATCH     32
#define DIM       9
#define UPS       300
#define F_LEN     400                 // L / UPS
#define NCHAIN    (BATCH * DIM)       // 288
#define N_SINE    (BATCH * L_LEN * DIM)  // 34,560,000
#define N_UV      (BATCH * L_LEN)        // 3,840,000
#define TWO_PI_F  6.28318530717958647692f

// ---------------------------------------------------------------------------
// Kernel A: per-(b,d) chain, cumsum of downsampled rad -> phase (radians).
// One wave (64 lanes) per chain; 7 chunks of 64 cover F_LEN=400.
// phase[chain*400 + f] = 2*pi * cumsum_{g<=f} frac(f0[b, g*300] * (d+1)/24000)
// ---------------------------------------------------------------------------
__global__ __launch_bounds__(64) void phase_scan_kernel(
    const float* __restrict__ f0, float* __restrict__ phase)
{
    const int chain = blockIdx.x;            // 0..287
    const int b = chain / DIM;
    const int d = chain - b * DIM;
    const float h = (float)(d + 1);
    const int lane = threadIdx.x;            // 0..63
    const float* f0b = f0 + (size_t)b * L_LEN;
    float* pout = phase + (size_t)chain * F_LEN;

    float running = 0.0f;
    #pragma unroll
    for (int c = 0; c < 7; ++c) {
        const int idx = c * 64 + lane;
        float v = 0.0f;
        if (idx < F_LEN) {
            const float r = f0b[idx * UPS] * h / 24000.0f;  // (f0*h)/SAMP_RATE
            v = r - floorf(r);                              // % 1.0 (f0 >= 0)
        }
        // inclusive wave scan over 64 lanes
        #pragma unroll
        for (int off = 1; off < 64; off <<= 1) {
            const float u = __shfl_up(v, off, 64);
            if (lane >= off) v += u;
        }
        const float ph = running + v;
        if (idx < F_LEN) pout[idx] = ph * TWO_PI_F;
        running += __shfl(v, 63, 64);
    }
}

// ---------------------------------------------------------------------------
// Kernel B: elementwise main pass. One thread = 4 consecutive (b,l,d) elems.
// float4 in (noise), float4 out (sine, noise_scaled), scalar uv at d==0.
// ---------------------------------------------------------------------------
__global__ __launch_bounds__(256) void sine_main_kernel(
    const float* __restrict__ f0, const float* __restrict__ noise,
    const float* __restrict__ phase, float* __restrict__ out_sine,
    float* __restrict__ out_uv, float* __restrict__ out_noise)
{
    const unsigned tid  = blockIdx.x * 256u + threadIdx.x;
    const unsigned base = tid * 4u;          // flat element index, 16B aligned
    // grid sized exactly: N_SINE / 4 threads, no tail

    const float4 nin = *reinterpret_cast<const float4*>(noise + base);
    const float nel[4] = {nin.x, nin.y, nin.z, nin.w};
    float sv[4], nv[4];

    #pragma unroll
    for (int e = 0; e < 4; ++e) {
        const unsigned t  = base + (unsigned)e;
        const unsigned bl = t / 9u;
        const unsigned d  = t - bl * 9u;
        const unsigned b  = bl / 120000u;
        const unsigned l  = bl - b * 120000u;
        const unsigned f  = l / 300u;
        const unsigned j  = l - f * 300u;

        const float f0v  = f0[bl];
        const bool voiced = (f0v > 0.0f);
        const float uvf  = voiced ? 1.0f : 0.0f;
        const float namp = voiced ? 0.003f : (0.1f / 3.0f);

        const float* pb = phase + (size_t)((b * 9u + d) * 400u);
        float ph;
        if (f < 399u) {
            const float p0 = pb[f];
            const float p1 = pb[f + 1u];
            ph = p0 + ((p1 - p0) / 300.0f) * (float)j;   // matches reference
        } else {
            ph = pb[399];                                // broadcast last phase
        }

        const float s  = sinf(ph) * 0.1f;
        const float nz = namp * nel[e];
        sv[e] = s * uvf + nz;
        nv[e] = nz;
        if (d == 0u) out_uv[bl] = uvf;
    }

    *reinterpret_cast<float4*>(out_sine + base)  = make_float4(sv[0], sv[1], sv[2], sv[3]);
    *reinterpret_cast<float4*>(out_noise + base) = make_float4(nv[0], nv[1], nv[2], nv[3]);
}

// ---------------------------------------------------------------------------
extern "C" void kernel_launch(void* const* d_in, const int* in_sizes, int n_in,
                              void* d_out, int out_size, void* d_ws, size_t ws_size,
                              hipStream_t stream)
{
    const float* f0    = (const float*)d_in[0];
    const float* noise = (const float*)d_in[1];
    float* out         = (float*)d_out;

    float* out_sine  = out;                      // (B,L,9)  34,560,000
    float* out_uv    = out + N_SINE;             // (B,L,1)   3,840,000
    float* out_noise = out + N_SINE + N_UV;      // (B,L,9)  34,560,000

    float* phase = (float*)d_ws;                 // 288*400 f32 = 460,800 B

    phase_scan_kernel<<<NCHAIN, 64, 0, stream>>>(f0, phase);

    const int nthreads = N_SINE / 4;             // 8,640,000
    sine_main_kernel<<<nthreads / 256, 256, 0, stream>>>(
        f0, noise, phase, out_sine, out_uv, out_noise);
}

// Round 3
// 422.508 us; speedup vs baseline: 1.0083x; 1.0083x over previous
//
#include <hip/hip_runtime.h>
#include <math.h>

// Problem constants (from reference)
#define L_LEN     120000
#define BATCH     32
#define DIM       9
#define UPS       300
#define F_LEN     400                 // L / UPS
#define NCHAIN    (BATCH * DIM)       // 288
#define N_SINE    (BATCH * L_LEN * DIM)  // 34,560,000
#define N_UV      (BATCH * L_LEN)        // 3,840,000
#define TWO_PI_F  6.28318530717958647692f

typedef float fx4 __attribute__((ext_vector_type(4)));  // native vec for nontemporal builtins

// ---------------------------------------------------------------------------
// Kernel A: per-(b,d) chain, cumsum of downsampled rad -> phase (radians).
// One wave (64 lanes) per chain; 7 chunks of 64 cover F_LEN=400.
// ---------------------------------------------------------------------------
__global__ __launch_bounds__(64) void phase_scan_kernel(
    const float* __restrict__ f0, float* __restrict__ phase)
{
    const int chain = blockIdx.x;            // 0..287
    const int b = chain / DIM;
    const int d = chain - b * DIM;
    const float h = (float)(d + 1);
    const int lane = threadIdx.x;            // 0..63
    const float* f0b = f0 + (size_t)b * L_LEN;
    float* pout = phase + (size_t)chain * F_LEN;

    float running = 0.0f;
    #pragma unroll
    for (int c = 0; c < 7; ++c) {
        const int idx = c * 64 + lane;
        float v = 0.0f;
        if (idx < F_LEN) {
            const float r = f0b[idx * UPS] * h / 24000.0f;  // (f0*h)/SAMP_RATE
            v = r - floorf(r);                              // % 1.0 (f0 >= 0)
        }
        #pragma unroll
        for (int off = 1; off < 64; off <<= 1) {
            const float u = __shfl_up(v, off, 64);
            if (lane >= off) v += u;
        }
        const float ph = running + v;
        if (idx < F_LEN) pout[idx] = ph * TWO_PI_F;
        running += __shfl(v, 63, 64);
    }
}

// ---------------------------------------------------------------------------
// Kernel C: uv output, fully vectorized (separated from main kernel so the
// main loop has no divergent 1-of-9 scalar stores).
// ---------------------------------------------------------------------------
__global__ __launch_bounds__(256) void uv_kernel(
    const float* __restrict__ f0, float* __restrict__ out_uv)
{
    const unsigned tid  = blockIdx.x * 256u + threadIdx.x;
    const unsigned base = tid * 4u;                  // < N_UV, exact grid
    const fx4 fv = *reinterpret_cast<const fx4*>(f0 + base);
    fx4 uv;
    uv.x = (fv.x > 0.0f) ? 1.0f : 0.0f;
    uv.y = (fv.y > 0.0f) ? 1.0f : 0.0f;
    uv.z = (fv.z > 0.0f) ? 1.0f : 0.0f;
    uv.w = (fv.w > 0.0f) ? 1.0f : 0.0f;
    __builtin_nontemporal_store(uv, reinterpret_cast<fx4*>(out_uv + base));
}

// ---------------------------------------------------------------------------
// Kernel B: elementwise main pass. One thread = 4 consecutive (b,l,d) elems.
// Index math done once per thread, then incremental updates (d wraps at 9).
// ---------------------------------------------------------------------------
__global__ __launch_bounds__(256) void sine_main_kernel(
    const float* __restrict__ f0, const float* __restrict__ noise,
    const float* __restrict__ phase, float* __restrict__ out_sine,
    float* __restrict__ out_noise)
{
    const unsigned tid  = blockIdx.x * 256u + threadIdx.x;
    const unsigned base = tid * 4u;          // flat element index, 16B aligned

    // one-time index decomposition (magic-mul divisions)
    unsigned bl = base / 9u;
    unsigned d  = base - bl * 9u;
    unsigned b  = bl / 120000u;
    unsigned l  = bl - b * 120000u;
    unsigned f  = l / 300u;
    unsigned j  = l - f * 300u;

    float f0v = f0[bl];

    const fx4 nin = __builtin_nontemporal_load(
        reinterpret_cast<const fx4*>(noise + base));
    const float nel[4] = {nin.x, nin.y, nin.z, nin.w};
    float sv[4], nv[4];

    #pragma unroll
    for (int e = 0; e < 4; ++e) {
        const bool voiced = (f0v > 0.0f);
        const float uvf  = voiced ? 1.0f : 0.0f;
        const float namp = voiced ? 0.003f : (0.1f / 3.0f);

        const float* pb = phase + (size_t)((b * 9u + d) * 400u);
        float ph;
        if (f < 399u) {
            const float p0 = pb[f];
            const float p1 = pb[f + 1u];
            ph = p0 + ((p1 - p0) * (1.0f / 300.0f)) * (float)j;
        } else {
            ph = pb[399];
        }

        const float s  = sinf(ph) * 0.1f;
        const float nz = namp * nel[e];
        sv[e] = s * uvf + nz;
        nv[e] = nz;

        // incremental index update for next element
        ++d;
        if (d == 9u) {
            d = 0u; ++bl; ++l; ++j;
            if (j == 300u) { j = 0u; ++f; }
            if (l == 120000u) { ++b; l = 0u; f = 0u; j = 0u; }
            f0v = f0[bl];
        }
    }

    fx4 svv; svv.x = sv[0]; svv.y = sv[1]; svv.z = sv[2]; svv.w = sv[3];
    fx4 nvv; nvv.x = nv[0]; nvv.y = nv[1]; nvv.z = nv[2]; nvv.w = nv[3];
    __builtin_nontemporal_store(svv, reinterpret_cast<fx4*>(out_sine + base));
    __builtin_nontemporal_store(nvv, reinterpret_cast<fx4*>(out_noise + base));
}

// ---------------------------------------------------------------------------
extern "C" void kernel_launch(void* const* d_in, const int* in_sizes, int n_in,
                              void* d_out, int out_size, void* d_ws, size_t ws_size,
                              hipStream_t stream)
{
    const float* f0    = (const float*)d_in[0];
    const float* noise = (const float*)d_in[1];
    float* out         = (float*)d_out;

    float* out_sine  = out;                      // (B,L,9)  34,560,000
    float* out_uv    = out + N_SINE;             // (B,L,1)   3,840,000
    float* out_noise = out + N_SINE + N_UV;      // (B,L,9)  34,560,000

    float* phase = (float*)d_ws;                 // 288*400 f32 = 460,800 B

    phase_scan_kernel<<<NCHAIN, 64, 0, stream>>>(f0, phase);
    uv_kernel<<<N_UV / 4 / 256, 256, 0, stream>>>(f0, out_uv);
    sine_main_kernel<<<N_SINE / 4 / 256, 256, 0, stream>>>(
        f0, noise, phase, out_sine, out_noise);
}

// Round 5
// 416.866 us; speedup vs baseline: 1.0219x; 1.0135x over previous
//
#include <hip/hip_runtime.h>
#include <math.h>

// Problem constants (from reference)
#define L_LEN     120000
#define BATCH     32
#define DIM       9
#define UPS       300
#define F_LEN     400                 // L / UPS
#define NCHAIN    (BATCH * DIM)       // 288
#define N_SINE    (BATCH * L_LEN * DIM)  // 34,560,000
#define N_UV      (BATCH * L_LEN)        // 3,840,000

typedef float fx4 __attribute__((ext_vector_type(4)));  // native vec for nontemporal builtins

// ---------------------------------------------------------------------------
// Kernel A: per-(b,d) chain, cumsum of downsampled rad -> phase.
// NOTE: phase is stored in REVOLUTIONS (cumsum of frac(f0*h/24000)), no 2*pi.
// One wave (64 lanes) per chain; 7 chunks of 64 cover F_LEN=400.
// ---------------------------------------------------------------------------
__global__ __launch_bounds__(64) void phase_scan_kernel(
    const float* __restrict__ f0, float* __restrict__ phase)
{
    const int chain = blockIdx.x;            // 0..287
    const int b = chain / DIM;
    const int d = chain - b * DIM;
    const float h = (float)(d + 1);
    const int lane = threadIdx.x;            // 0..63
    const float* f0b = f0 + (size_t)b * L_LEN;
    float* pout = phase + (size_t)chain * F_LEN;

    float running = 0.0f;
    #pragma unroll
    for (int c = 0; c < 7; ++c) {
        const int idx = c * 64 + lane;
        float v = 0.0f;
        if (idx < F_LEN) {
            const float r = f0b[idx * UPS] * h / 24000.0f;  // (f0*h)/SAMP_RATE
            v = r - floorf(r);                              // % 1.0 (f0 >= 0)
        }
        #pragma unroll
        for (int off = 1; off < 64; off <<= 1) {
            const float u = __shfl_up(v, off, 64);
            if (lane >= off) v += u;
        }
        const float ph = running + v;
        if (idx < F_LEN) pout[idx] = ph;     // revolutions
        running += __shfl(v, 63, 64);
    }
}

// ---------------------------------------------------------------------------
// Kernel C: uv output, fully vectorized.
// ---------------------------------------------------------------------------
__global__ __launch_bounds__(256) void uv_kernel(
    const float* __restrict__ f0, float* __restrict__ out_uv)
{
    const unsigned tid  = blockIdx.x * 256u + threadIdx.x;
    const unsigned base = tid * 4u;                  // < N_UV, exact grid
    const fx4 fv = *reinterpret_cast<const fx4*>(f0 + base);
    fx4 uv;
    uv.x = (fv.x > 0.0f) ? 1.0f : 0.0f;
    uv.y = (fv.y > 0.0f) ? 1.0f : 0.0f;
    uv.z = (fv.z > 0.0f) ? 1.0f : 0.0f;
    uv.w = (fv.w > 0.0f) ? 1.0f : 0.0f;
    __builtin_nontemporal_store(uv, reinterpret_cast<fx4*>(out_uv + base));
}

// ---------------------------------------------------------------------------
// Kernel B: elementwise main pass. One thread = 4 consecutive (b,l,d) elems.
// Phase interp in revolutions; sin via fract + v_sin_f32 (sin(2*pi*x)).
// ---------------------------------------------------------------------------
__global__ __launch_bounds__(256) void sine_main_kernel(
    const float* __restrict__ f0, const float* __restrict__ noise,
    const float* __restrict__ phase, float* __restrict__ out_sine,
    float* __restrict__ out_noise)
{
    const unsigned tid  = blockIdx.x * 256u + threadIdx.x;
    const unsigned base = tid * 4u;          // flat element index, 16B aligned

    const fx4 nin = __builtin_nontemporal_load(
        reinterpret_cast<const fx4*>(noise + base));
    const float nel[4] = {nin.x, nin.y, nin.z, nin.w};
    float sv[4], nv[4];

    #pragma unroll
    for (int e = 0; e < 4; ++e) {
        const unsigned t  = base + (unsigned)e;
        const unsigned bl = t / 9u;
        const unsigned d  = t - bl * 9u;
        const unsigned b  = bl / 120000u;
        const unsigned l  = bl - b * 120000u;
        const unsigned f  = l / 300u;
        const unsigned j  = l - f * 300u;

        const float f0v   = f0[bl];
        const bool voiced = (f0v > 0.0f);
        const float uvf   = voiced ? 1.0f : 0.0f;
        const float namp  = voiced ? 0.003f : (0.1f / 3.0f);

        const float* pb = phase + (size_t)((b * 9u + d) * 400u);
        float ph;                                   // revolutions
        if (f < 399u) {
            const float p0 = pb[f];
            const float p1 = pb[f + 1u];
            ph = p0 + ((p1 - p0) * (1.0f / 300.0f)) * (float)j;
        } else {
            ph = pb[399];
        }

        // sin(2*pi*ph): fract to [0,1) (hw domain), then v_sin_f32
        const float fr = ph - floorf(ph);
        const float s  = __builtin_amdgcn_sinf(fr) * 0.1f;

        const float nz = namp * nel[e];
        sv[e] = s * uvf + nz;
        nv[e] = nz;
    }

    fx4 svv; svv.x = sv[0]; svv.y = sv[1]; svv.z = sv[2]; svv.w = sv[3];
    fx4 nvv; nvv.x = nv[0]; nvv.y = nv[1]; nvv.z = nv[2]; nvv.w = nv[3];
    __builtin_nontemporal_store(svv, reinterpret_cast<fx4*>(out_sine + base));
    __builtin_nontemporal_store(nvv, reinterpret_cast<fx4*>(out_noise + base));
}

// ---------------------------------------------------------------------------
extern "C" void kernel_launch(void* const* d_in, const int* in_sizes, int n_in,
                              void* d_out, int out_size, void* d_ws, size_t ws_size,
                              hipStream_t stream)
{
    const float* f0    = (const float*)d_in[0];
    const float* noise = (const float*)d_in[1];
    float* out         = (float*)d_out;

    float* out_sine  = out;                      // (B,L,9)  34,560,000
    float* out_uv    = out + N_SINE;             // (B,L,1)   3,840,000
    float* out_noise = out + N_SINE + N_UV;      // (B,L,9)  34,560,000

    float* phase = (float*)d_ws;                 // 288*400 f32 = 460,800 B

    phase_scan_kernel<<<NCHAIN, 64, 0, stream>>>(f0, phase);
    uv_kernel<<<N_UV / 4 / 256, 256, 0, stream>>>(f0, out_uv);
    sine_main_kernel<<<N_SINE / 4 / 256, 256, 0, stream>>>(
        f0, noise, phase, out_sine, out_noise);
}